// Round 12
// baseline (476.566 us; speedup 1.0000x reference)
//
#include <hip/hip_runtime.h>
#include <hip/hip_bf16.h>
#include <math.h>

#define CIN   2048
#define CMID  1024
#define NB    32
#define HWSP  196
#define NPOS  6272      // 32*196
#define WELEM 2097152   // CMID*CIN
#define NSTEP 288       // K32-steps per z-chunk (total K=18432 split in 2)

typedef __attribute__((ext_vector_type(4))) float f32x4;
typedef __attribute__((ext_vector_type(8))) short short8;
typedef __attribute__((ext_vector_type(4))) float float4v;

typedef const __attribute__((address_space(1))) unsigned int* as1_u32p;
typedef __attribute__((address_space(3))) unsigned int* as3_u32p;

__device__ __forceinline__ void gload_lds16(const void* g, void* l) {
  __builtin_amdgcn_global_load_lds((as1_u32p)g, (as3_u32p)l, 16, 0, 0);
}

// ---------------- pack weights: w1 -> Wpack[9][1024][2048] bf16 via LDS transpose (coalesced),
// BN fold, head-weight transpose
__global__ __launch_bounds__(256) void pack_w(
    const float* __restrict__ w1, const float* __restrict__ b1,
    const float* __restrict__ g1, const float* __restrict__ be1,
    const float* __restrict__ mu1, const float* __restrict__ va1,
    const float* __restrict__ wsel, const float* __restrict__ wbox,
    __hip_bfloat16* __restrict__ Wp, float* __restrict__ inv1,
    float* __restrict__ add1, float* __restrict__ Wh)
{
  __shared__ float lw[2304];     // 256 gid x 9 taps
  const int gid0 = blockIdx.x * 256;
  const float4v* src4 = (const float4v*)(w1 + (long)gid0 * 9);
  float4v* l4 = (float4v*)lw;
  #pragma unroll
  for (int i = 0; i < 3; ++i) {
    int idx = i * 256 + threadIdx.x;
    if (idx < 576) l4[idx] = src4[idx];
  }
  __syncthreads();
  const int gid = gid0 + threadIdx.x;
  float v[9];
  #pragma unroll
  for (int k = 0; k < 9; ++k) v[k] = lw[threadIdx.x * 9 + k];
  #pragma unroll
  for (int k = 0; k < 9; ++k)
    Wp[(long)k * WELEM + gid] = __float2bfloat16(v[k]);

  if (gid < CMID) {
    float iv = g1[gid] / sqrtf(va1[gid] + 1e-5f);
    inv1[gid] = iv;
    add1[gid] = b1[gid] * iv + be1[gid] - mu1[gid] * iv;
  }
  if (gid < CMID * 54) {
    int co = gid / 54, o = gid % 54;
    Wh[gid] = (o < 18) ? wsel[o * CMID + co] : wbox[(o - 18) * CMID + co];
  }
}

// ---------------- pack x: NCHW fp32 -> Xpad[32][16][16][2048] bf16 (zero border)
__global__ __launch_bounds__(256) void pack_x(
    const float* __restrict__ x, __hip_bfloat16* __restrict__ Xp)
{
  __shared__ __hip_bfloat16 lx[64 * HWSP];
  const int n = blockIdx.x;      // 0..31
  const int cc = blockIdx.y;     // 0..31
  const int ci0 = cc * 64;
  const float* src = x + ((long)n * CIN + ci0) * HWSP;
  for (int i = threadIdx.x; i < 64 * HWSP; i += 256)
    lx[i] = __float2bfloat16(src[i]);
  __syncthreads();
  const int ci = threadIdx.x & 63;
  const int pq = threadIdx.x >> 6;   // 0..3
  __hip_bfloat16* dst = Xp + (long)n * 256 * CIN + ci0 + ci;
  const __hip_bfloat16 z = __float2bfloat16(0.f);
  #pragma unroll
  for (int k = 0; k < 64; ++k) {
    int pos = k * 4 + pq;
    int y = pos >> 4, xx = pos & 15;
    __hip_bfloat16 v = z;
    if (y >= 1 && y <= 14 && xx >= 1 && xx <= 14)
      v = lx[ci * HWSP + (y - 1) * 14 + (xx - 1)];
    dst[(long)pos * CIN] = v;
  }
}

// ---------------- conv 3x3 as shifted GEMMs, split-K halves (288 BK32-steps each)
// 128x128 tile, 4 waves x (64x64), 16x16x32 bf16 MFMA.
// Ring-3 LDS (48KB) + REGISTER FRAG READ-AHEAD: step s MFMAs frags read at step s-1
// while issuing reads for s+1 — LDS latency hides under the MFMA cluster.
// One raw barrier + lgkmcnt(0) + counted vmcnt(4) per step. XCD remap from R8.
__global__ __launch_bounds__(256, 2) void conv_mfma(
    const __hip_bfloat16* __restrict__ Wp,
    const __hip_bfloat16* __restrict__ Xp,
    __hip_bfloat16* __restrict__ hout0,
    __hip_bfloat16* __restrict__ hout1)
{
  __shared__ char smem[3 * 16384];   // ring-3: A 8KB + B 8KB per step

  const int t = threadIdx.x;
  // grid.x = 448: r = XCD slot, q>>3 = ntile column, q&7 = mtile
  const int bx = blockIdx.x;
  const int r  = bx & 7;
  const int q  = bx >> 3;          // 0..55
  const int kidx = q >> 3;         // 0..6
  int mtile = q & 7;
  int ntile;
  if (kidx < 6) {
    ntile = r + 8 * kidx;          // XCD r owns ntiles {r, r+8, ..., r+40}
  } else {
    if (r != (q & 7)) return;      // ntile 48: one block per XCD (balanced)
    ntile = 48;
  }
  const int z = blockIdx.y;        // 0..1
  const int lane = t & 63;
  const int wv = t >> 6;          // 0..3
  const int wr2 = wv >> 1;        // 0..1 -> M offset *64
  const int wc2 = wv & 1;         // 0..1 -> N offset *64

  // staging: thread t covers rows (t>>2)(+64 for B's 2nd half), XOR-preswizzled source
  const int srow = t >> 2;                                   // 0..63
  const int swb = ((t & 3) << 4) ^ ((srow & 6) << 3);        // byte offset in 64B row

  const long arowbase = (long)(mtile * 128 + srow) * CIN + (swb >> 1);

  long bbase[2];
  #pragma unroll
  for (int i = 0; i < 2; ++i) {
    int jj = ntile * 128 + srow + 64 * i;
    int n0 = jj / HWSP, p0 = jj % HWSP;
    int hh = p0 / 14, ww = p0 % 14;
    bbase[i] = (long)(n0 * 256 + hh * 16 + ww) * CIN + (swb >> 1);
  }

  // frag-read swizzle constant
  const int fr = lane & 15;
  const int ksl = lane >> 4;                                 // 0..3
  const int kgsw = ((ksl << 4) ^ ((fr & 6) << 3));

  f32x4 acc[4][4] = {};
  short8 aA[4], bA[4], aB[4], bB[4];   // double-buffered frags (named, static)

  const int g0 = z * NSTEP;

  #define STAGE(gv, db) do {                                                    \
    int g_ = (gv);                                                              \
    int kt_ = g_ >> 6;                                                          \
    int ck_ = (g_ & 63) << 5;                                                   \
    int kh_ = (kt_ * 11) >> 5;                                                  \
    int kw_ = kt_ - kh_ * 3;                                                    \
    char* d_ = (db);                                                            \
    const __hip_bfloat16* ap_ = Wp + (long)kt_ * WELEM + arowbase + ck_;        \
    gload_lds16(ap_,             d_ + t * 16);                                  \
    gload_lds16(ap_ + 64L * CIN, d_ + 4096 + t * 16);                           \
    long boff_ = (long)(kh_ * 16 + kw_) * CIN + ck_;                            \
    gload_lds16(Xp + bbase[0] + boff_, d_ + 8192 + t * 16);                     \
    gload_lds16(Xp + bbase[1] + boff_, d_ + 12288 + t * 16);                    \
  } while (0)

  #define READF(av, bv, cb) do {                                                \
    const char* cb_ = (cb);                                                     \
    _Pragma("unroll")                                                           \
    for (int i = 0; i < 4; ++i)                                                 \
      av[i] = *(const short8*)(cb_ + (wr2 * 64 + i * 16 + fr) * 64 + kgsw);     \
    _Pragma("unroll")                                                           \
    for (int i = 0; i < 4; ++i)                                                 \
      bv[i] = *(const short8*)(cb_ + 8192 + (wc2 * 64 + i * 16 + fr) * 64 + kgsw); \
  } while (0)

  #define MFMA16(av, bv) do {                                                   \
    __builtin_amdgcn_s_setprio(1);                                              \
    _Pragma("unroll")                                                           \
    for (int m = 0; m < 4; ++m)                                                 \
      _Pragma("unroll")                                                         \
      for (int n = 0; n < 4; ++n)                                               \
        acc[m][n] = __builtin_amdgcn_mfma_f32_16x16x32_bf16(av[m], bv[n], acc[m][n], 0, 0, 0); \
    __builtin_amdgcn_s_setprio(0);                                              \
  } while (0)

  #define WAITV4() asm volatile("s_waitcnt vmcnt(4)" ::: "memory")
  #define WAITV0() asm volatile("s_waitcnt vmcnt(0)" ::: "memory")
  #define LGKM0()  asm volatile("s_waitcnt lgkmcnt(0)" ::: "memory")
  #define BAR() do { asm volatile("" ::: "memory");                             \
                     __builtin_amdgcn_s_barrier();                              \
                     asm volatile("" ::: "memory");                             \
                     __builtin_amdgcn_sched_barrier(0); } while (0)

  char* buf0 = smem;            // buf for step s   (rotates)
  char* buf1 = smem + 16384;    // buf for step s+1
  char* buf2 = smem + 32768;    // buf for step s+2

  // prologue: stage(0),(1); publish (0); preload frags(0) into A-set
  STAGE(g0 + 0, buf0);
  STAGE(g0 + 1, buf1);
  WAITV4();                    // retires stage(0); stage(1) in flight
  LGKM0(); BAR();
  READF(aA, bA, buf0);

  for (int s = 0; s < NSTEP - 2; s += 2) {
    // even step s: MFMA frags(s) [A-set], read frags(s+1) -> B-set
    STAGE(g0 + s + 2, buf2);   // outstanding: stage(s+1) 4 + these 4 = 8
    WAITV4();                  // retires stage(s+1)
    LGKM0();                   // my reads of buf2's old contents (frags s-1) drained
    BAR();                     // publish stage(s+1); fence buf2 overwrite vs all waves
    READF(aB, bB, buf1);
    MFMA16(aA, bA);
    // odd step s+1: MFMA frags(s+1) [B-set], read frags(s+2) -> A-set
    STAGE(g0 + s + 3, buf0);   // buf0 holds frags(s), last read pre-BAR above... (s+3)%3 == s%3
    WAITV4();                  // retires stage(s+2)
    LGKM0();
    BAR();
    READF(aA, bA, buf2);
    MFMA16(aB, bB);
    // rotate ring: (buf0,buf1,buf2) <- (buf2,buf0,buf1)
    char* tmp = buf2; buf2 = buf1; buf1 = buf0; buf0 = tmp;
  }
  // tail: step NSTEP-2 (frags in A-set, stage(NSTEP-1) outstanding)
  WAITV0();
  LGKM0(); BAR();
  READF(aB, bB, buf1);
  MFMA16(aA, bA);
  // step NSTEP-1
  MFMA16(aB, bB);

  // epilogue: bf16 raw conv partials (BN/ReLU fused in head)
  __hip_bfloat16* dsth = z ? hout1 : hout0;
  const int rg = ksl * 4;
  #pragma unroll
  for (int m = 0; m < 4; ++m) {
    const int co0 = mtile * 128 + wr2 * 64 + m * 16 + rg;
    #pragma unroll
    for (int r_ = 0; r_ < 4; ++r_) {
      const int co = co0 + r_;
      #pragma unroll
      for (int n = 0; n < 4; ++n) {
        const int j = ntile * 128 + wc2 * 64 + n * 16 + fr;
        dsth[(long)co * NPOS + j] = __float2bfloat16(acc[m][n][r_]);
      }
    }
  }
  #undef STAGE
  #undef READF
  #undef MFMA16
  #undef WAITV4
  #undef WAITV0
  #undef LGKM0
  #undef BAR
}

// ---------------- fused 1x1 heads: sum partials + BN1/ReLU + heads + softmax/BN/reshape
__global__ __launch_bounds__(256) void head_fused(
    const __hip_bfloat16* __restrict__ h0, const __hip_bfloat16* __restrict__ h1,
    const float* __restrict__ Wh,
    const float* __restrict__ inv1, const float* __restrict__ add1,
    const float* __restrict__ bsel, const float* __restrict__ bbox,
    const float* __restrict__ gb, const float* __restrict__ beb,
    const float* __restrict__ mub, const float* __restrict__ vab,
    float* __restrict__ out)
{
  __shared__ float red[4 * 64 * 54];
  const int t = threadIdx.x;
  const int jl = t & 63;
  const int cg = __builtin_amdgcn_readfirstlane(t >> 6);  // 0..3, wave-uniform
  const int j0 = blockIdx.x * 64;
  const int j = j0 + jl;

  float acc[54];
  #pragma unroll
  for (int o = 0; o < 54; ++o) acc[o] = 0.f;

  const __hip_bfloat16* hp0 = h0 + (long)(cg * 256) * NPOS + j;
  const __hip_bfloat16* hp1 = h1 + (long)(cg * 256) * NPOS + j;
  const float* wp = Wh + cg * 256 * 54;
  const float* ivp = inv1 + cg * 256;
  const float* adp = add1 + cg * 256;
  for (int i = 0; i < 256; ++i) {
    float hv = __bfloat162float(hp0[(long)i * NPOS]) + __bfloat162float(hp1[(long)i * NPOS]);
    hv = fmaxf(hv * ivp[i] + adp[i], 0.f);   // fused bias+BN1+ReLU
    const float* wr_ = wp + i * 54;
    #pragma unroll
    for (int o = 0; o < 54; ++o) acc[o] += hv * wr_[o];
  }
  #pragma unroll
  for (int o = 0; o < 54; ++o) red[(cg * 64 + jl) * 54 + o] = acc[o];
  __syncthreads();

  // scores: 64 j x 9 pairs -> relu -> softmax over pair
  for (int idx = t; idx < 576; idx += 256) {
    int jj = idx / 9, pr = idx % 9;
    float s0 = bsel[2 * pr], s1 = bsel[2 * pr + 1];
    #pragma unroll
    for (int c = 0; c < 4; ++c) {
      s0 += red[(c * 64 + jj) * 54 + 2 * pr];
      s1 += red[(c * 64 + jj) * 54 + 2 * pr + 1];
    }
    s0 = fmaxf(s0, 0.f); s1 = fmaxf(s1, 0.f);
    float mx = fmaxf(s0, s1);
    float e0 = expf(s0 - mx), e1 = expf(s1 - mx);
    float inv = 1.f / (e0 + e1);
    int jg = j0 + jj;
    int nn = jg / HWSP, p = jg % HWSP;
    long off = ((long)nn * 1764 + p * 9 + pr) * 2;
    out[off] = e0 * inv;
    out[off + 1] = e1 * inv;
  }

  // boxes: 64 j x 36 -> BN -> relu -> *419
  float* outb = out + (long)NB * 1764 * 2;
  for (int idx = t; idx < 2304; idx += 256) {
    int jj = idx / 36, o = idx % 36;
    float v = bbox[o];
    #pragma unroll
    for (int c = 0; c < 4; ++c) v += red[(c * 64 + jj) * 54 + 18 + o];
    float iv = gb[o] / sqrtf(vab[o] + 1e-5f);
    v = v * iv + (beb[o] - mub[o] * iv);
    v = fmaxf(v, 0.f) * 419.f;
    int jg = j0 + jj;
    int nn = jg / HWSP, p = jg % HWSP;
    outb[((long)nn * 1764 + p * 9 + (o >> 2)) * 4 + (o & 3)] = v;
  }
}

extern "C" void kernel_launch(void* const* d_in, const int* in_sizes, int n_in,
                              void* d_out, int out_size, void* d_ws, size_t ws_size,
                              hipStream_t stream) {
  const float* x    = (const float*)d_in[0];
  const float* w1   = (const float*)d_in[1];
  const float* b1   = (const float*)d_in[2];
  const float* g1   = (const float*)d_in[3];
  const float* be1  = (const float*)d_in[4];
  const float* mu1  = (const float*)d_in[5];
  const float* va1  = (const float*)d_in[6];
  const float* wsel = (const float*)d_in[7];
  const float* bsel = (const float*)d_in[8];
  const float* wbox = (const float*)d_in[9];
  const float* bbox = (const float*)d_in[10];
  const float* gb   = (const float*)d_in[11];
  const float* beb  = (const float*)d_in[12];
  const float* mub  = (const float*)d_in[13];
  const float* vab  = (const float*)d_in[14];

  char* ws = (char*)d_ws;
  __hip_bfloat16* Wp = (__hip_bfloat16*)(ws);                    // 9*1024*2048*2   = 37748736
  __hip_bfloat16* Xp = (__hip_bfloat16*)(ws + 37748736);         // 32*256*2048*2   = 33554432
  __hip_bfloat16* hb0 = (__hip_bfloat16*)(ws + 71303168);        // 1024*6272*2     = 12845056
  __hip_bfloat16* hb1 = (__hip_bfloat16*)(ws + 84148224);        // 1024*6272*2     = 12845056
  float* inv1        = (float*)(ws + 96993280);                  // 4096
  float* add1        = (float*)(ws + 96997376);                  // 4096
  float* Wh          = (float*)(ws + 97001472);                  // 1024*54*4       = 221184

  hipLaunchKernelGGL(pack_w, dim3(8192), dim3(256), 0, stream,
                     w1, b1, g1, be1, mu1, va1, wsel, wbox, Wp, inv1, add1, Wh);
  hipLaunchKernelGGL(pack_x, dim3(32, 32), dim3(256), 0, stream, x, Xp);
  hipLaunchKernelGGL(conv_mfma, dim3(448, 2), dim3(256), 0, stream,
                     Wp, Xp, hb0, hb1);
  hipLaunchKernelGGL(head_fused, dim3(98), dim3(256), 0, stream,
                     hb0, hb1, Wh, inv1, add1, bsel, bbox, gb, beb, mub, vab, (float*)d_out);
}

// Round 13
// 413.166 us; speedup vs baseline: 1.1534x; 1.1534x over previous
//
#include <hip/hip_runtime.h>
#include <hip/hip_bf16.h>
#include <math.h>

#define CIN   2048
#define CMID  1024
#define NB    32
#define HWSP  196
#define NPOS  6272      // 32*196
#define WELEM 2097152   // CMID*CIN
#define NST64 144       // K64-steps per z-chunk (total K=18432 split in 2)

typedef __attribute__((ext_vector_type(4))) float f32x4;
typedef __attribute__((ext_vector_type(8))) short short8;
typedef __attribute__((ext_vector_type(4))) float float4v;

typedef const __attribute__((address_space(1))) unsigned int* as1_u32p;
typedef __attribute__((address_space(3))) unsigned int* as3_u32p;

__device__ __forceinline__ void gload_lds16(const void* g, void* l) {
  __builtin_amdgcn_global_load_lds((as1_u32p)g, (as3_u32p)l, 16, 0, 0);
}

// ---------------- fused packing: blocks [0,8192) pack W (LDS-transposed), blocks [8192,9216) pack X
__global__ __launch_bounds__(256) void pack_all(
    const float* __restrict__ w1, const float* __restrict__ b1,
    const float* __restrict__ g1, const float* __restrict__ be1,
    const float* __restrict__ mu1, const float* __restrict__ va1,
    const float* __restrict__ wsel, const float* __restrict__ wbox,
    const float* __restrict__ x,
    __hip_bfloat16* __restrict__ Wp, float* __restrict__ inv1,
    float* __restrict__ add1, float* __restrict__ Wh,
    __hip_bfloat16* __restrict__ Xp)
{
  __shared__ char shm[25088];
  if (blockIdx.x < 8192) {
    // ---- pack W: w1 -> Wpack[9][1024][2048] bf16, BN fold, head-weight transpose
    float* lw = (float*)shm;     // 256 gid x 9 taps
    const int gid0 = blockIdx.x * 256;
    const float4v* src4 = (const float4v*)(w1 + (long)gid0 * 9);
    float4v* l4 = (float4v*)lw;
    #pragma unroll
    for (int i = 0; i < 3; ++i) {
      int idx = i * 256 + threadIdx.x;
      if (idx < 576) l4[idx] = src4[idx];
    }
    __syncthreads();
    const int gid = gid0 + threadIdx.x;
    float v[9];
    #pragma unroll
    for (int k = 0; k < 9; ++k) v[k] = lw[threadIdx.x * 9 + k];
    #pragma unroll
    for (int k = 0; k < 9; ++k)
      Wp[(long)k * WELEM + gid] = __float2bfloat16(v[k]);

    if (gid < CMID) {
      float iv = g1[gid] / sqrtf(va1[gid] + 1e-5f);
      inv1[gid] = iv;
      add1[gid] = b1[gid] * iv + be1[gid] - mu1[gid] * iv;
    }
    if (gid < CMID * 54) {
      int co = gid / 54, o = gid % 54;
      Wh[gid] = (o < 18) ? wsel[o * CMID + co] : wbox[(o - 18) * CMID + co];
    }
  } else {
    // ---- pack X: NCHW fp32 -> Xpad[32][16][16][2048] bf16 (zero border)
    __hip_bfloat16* lx = (__hip_bfloat16*)shm;   // 64 ci x 196 pos
    const int b = blockIdx.x - 8192;
    const int n = b >> 5;          // 0..31
    const int cc = b & 31;         // 0..31
    const int ci0 = cc * 64;
    const float* src = x + ((long)n * CIN + ci0) * HWSP;
    for (int i = threadIdx.x; i < 64 * HWSP; i += 256)
      lx[i] = __float2bfloat16(src[i]);
    __syncthreads();
    const int ci = threadIdx.x & 63;
    const int pq = threadIdx.x >> 6;   // 0..3
    __hip_bfloat16* dst = Xp + (long)n * 256 * CIN + ci0 + ci;
    const __hip_bfloat16 z = __float2bfloat16(0.f);
    #pragma unroll
    for (int k = 0; k < 64; ++k) {
      int pos = k * 4 + pq;
      int y = pos >> 4, xx = pos & 15;
      __hip_bfloat16 v = z;
      if (y >= 1 && y <= 14 && xx >= 1 && xx <= 14)
        v = lx[ci * HWSP + (y - 1) * 14 + (xx - 1)];
      dst[(long)pos * CIN] = v;
    }
  }
}

// ---------------- conv 3x3 as shifted GEMMs, split-K halves (144 BK64-steps each)
// 128x128 tile, 4 waves x (64x64), 16x16x32 bf16 MFMA.
// R11 skeleton (BK=64 dbuf 2x32KB, per step: 2 barriers, 1 counted vmcnt(4), setprio
// MFMA clusters) + HOISTED ds_reads: both k-half frag sets read up front so half1's
// MFMA cluster runs with zero LDS wait and half1's reads hide under half0's cluster.
__global__ __launch_bounds__(256, 2) void conv_mfma(
    const __hip_bfloat16* __restrict__ Wp,
    const __hip_bfloat16* __restrict__ Xp,
    __hip_bfloat16* __restrict__ hout0,
    __hip_bfloat16* __restrict__ hout1)
{
  __shared__ char smem[2 * 32768];   // per buffer: A_k0 8K | A_k1 8K | B_k0 8K | B_k1 8K

  const int t = threadIdx.x;
  // grid.x = 448: r = XCD slot, q>>3 = ntile column, q&7 = mtile
  const int bx = blockIdx.x;
  const int r  = bx & 7;
  const int q  = bx >> 3;          // 0..55
  const int kidx = q >> 3;         // 0..6
  int mtile = q & 7;
  int ntile;
  if (kidx < 6) {
    ntile = r + 8 * kidx;          // XCD r owns ntiles {r, r+8, ..., r+40}
  } else {
    if (r != (q & 7)) return;      // ntile 48: one block per XCD (balanced)
    ntile = 48;
  }
  const int z = blockIdx.y;        // 0..1
  const int lane = t & 63;
  const int wv = t >> 6;          // 0..3
  const int wr2 = wv >> 1;        // 0..1 -> M offset *64
  const int wc2 = wv & 1;         // 0..1 -> N offset *64

  // staging: thread t covers rows (t>>2)(+64), 16B chunk (t&3), XOR-preswizzled source
  const int srow = t >> 2;                                   // 0..63
  const int swb = ((t & 3) << 4) ^ ((srow & 6) << 3);        // byte offset in 64B row

  const long arowbase = (long)(mtile * 128 + srow) * CIN + (swb >> 1);

  long bbase[2];
  #pragma unroll
  for (int i = 0; i < 2; ++i) {
    int jj = ntile * 128 + srow + 64 * i;
    int n0 = jj / HWSP, p0 = jj % HWSP;
    int hh = p0 / 14, ww = p0 % 14;
    bbase[i] = (long)(n0 * 256 + hh * 16 + ww) * CIN + (swb >> 1);
  }

  // frag-read swizzle constant
  const int fr = lane & 15;
  const int ksl = lane >> 4;                                 // 0..3
  const int kgsw = ((ksl << 4) ^ ((fr & 6) << 3));

  f32x4 acc[4][4] = {};
  short8 aA[4], bA[4], aB[4], bB[4];   // frag sets: half0 -> A-set, half1 -> B-set

  const int g0 = z * NST64;

  #define STAGE_A(gv, bi) do {                                                  \
    int g_ = (gv);                                                              \
    int kt_ = g_ >> 5;                                                          \
    int ck_ = (g_ & 31) << 6;                                                   \
    char* d_ = smem + (bi) * 32768;                                             \
    const __hip_bfloat16* ap_ = Wp + (long)kt_ * WELEM + arowbase + ck_;        \
    _Pragma("unroll")                                                           \
    for (int h_ = 0; h_ < 2; ++h_)                                              \
      _Pragma("unroll")                                                         \
      for (int i_ = 0; i_ < 2; ++i_)                                            \
        gload_lds16(ap_ + h_ * 32 + (long)i_ * 64 * CIN,                        \
                    d_ + h_ * 8192 + i_ * 4096 + t * 16);                       \
  } while (0)

  #define STAGE_B(gv, bi) do {                                                  \
    int g_ = (gv);                                                              \
    int kt_ = g_ >> 5;                                                          \
    int ck_ = (g_ & 31) << 6;                                                   \
    int kh_ = (kt_ * 11) >> 5;                                                  \
    int kw_ = kt_ - kh_ * 3;                                                    \
    char* d_ = smem + (bi) * 32768 + 16384;                                     \
    long boff_ = (long)(kh_ * 16 + kw_) * CIN + ck_;                            \
    _Pragma("unroll")                                                           \
    for (int h_ = 0; h_ < 2; ++h_)                                              \
      _Pragma("unroll")                                                         \
      for (int i_ = 0; i_ < 2; ++i_)                                            \
        gload_lds16(Xp + bbase[i_] + boff_ + h_ * 32,                           \
                    d_ + h_ * 8192 + i_ * 4096 + t * 16);                       \
  } while (0)

  // read BOTH halves: half0 -> (aA,bA), half1 -> (aB,bB)
  #define READ_H2(bi) do {                                                      \
    const char* c0_ = smem + (bi) * 32768;                                      \
    const char* c1_ = c0_ + 8192;                                               \
    _Pragma("unroll")                                                           \
    for (int i = 0; i < 4; ++i)                                                 \
      aA[i] = *(const short8*)(c0_ + (wr2 * 64 + i * 16 + fr) * 64 + kgsw);     \
    _Pragma("unroll")                                                           \
    for (int i = 0; i < 4; ++i)                                                 \
      bA[i] = *(const short8*)(c0_ + 16384 + (wc2 * 64 + i * 16 + fr) * 64 + kgsw); \
    _Pragma("unroll")                                                           \
    for (int i = 0; i < 4; ++i)                                                 \
      aB[i] = *(const short8*)(c1_ + (wr2 * 64 + i * 16 + fr) * 64 + kgsw);     \
    _Pragma("unroll")                                                           \
    for (int i = 0; i < 4; ++i)                                                 \
      bB[i] = *(const short8*)(c1_ + 16384 + (wc2 * 64 + i * 16 + fr) * 64 + kgsw); \
  } while (0)

  #define MFMA16(av, bv) do {                                                   \
    __builtin_amdgcn_s_setprio(1);                                              \
    _Pragma("unroll")                                                           \
    for (int m = 0; m < 4; ++m)                                                 \
      _Pragma("unroll")                                                         \
      for (int n = 0; n < 4; ++n)                                               \
        acc[m][n] = __builtin_amdgcn_mfma_f32_16x16x32_bf16(av[m], bv[n], acc[m][n], 0, 0, 0); \
    __builtin_amdgcn_s_setprio(0);                                              \
  } while (0)

  #define WAITV4() asm volatile("s_waitcnt vmcnt(4)" ::: "memory")
  #define WAITV0() asm volatile("s_waitcnt vmcnt(0)" ::: "memory")
  #define BAR() do { asm volatile("" ::: "memory");                             \
                     __builtin_amdgcn_s_barrier();                              \
                     asm volatile("" ::: "memory"); } while (0)

  // prologue: stage(0) fully (8 loads)
  STAGE_A(g0 + 0, 0);
  STAGE_B(g0 + 0, 0);

  for (int s = 0; s < NST64 - 1; ++s) {
    const int c = s & 1, n = c ^ 1;
    STAGE_A(g0 + s + 1, n);     // outstanding: stage(s) 8 + 4 = 12
    WAITV4();                   // retires stage(s); my 4 A-loads remain in flight
    BAR();                      // stage(s) visible; prev-step reads done
    READ_H2(c);                 // 16 ds_reads: half1's overlap under half0's cluster
    MFMA16(aA, bA);             // fine-grained lgkmcnt from compiler
    STAGE_B(g0 + s + 1, n);     // outstanding: 8
    BAR();                      // reads of buf[c] complete before next-step overwrite
    MFMA16(aB, bB);             // zero LDS wait — frags already in regs
  }
  // final step
  {
    const int c = (NST64 - 1) & 1;
    WAITV0(); BAR();
    READ_H2(c);
    MFMA16(aA, bA);
    MFMA16(aB, bB);
  }

  // epilogue: bf16 raw conv partials (BN/ReLU fused in head)
  __hip_bfloat16* dsth = z ? hout1 : hout0;
  const int rg = ksl * 4;
  #pragma unroll
  for (int m = 0; m < 4; ++m) {
    const int co0 = mtile * 128 + wr2 * 64 + m * 16 + rg;
    #pragma unroll
    for (int r_ = 0; r_ < 4; ++r_) {
      const int co = co0 + r_;
      #pragma unroll
      for (int n = 0; n < 4; ++n) {
        const int j = ntile * 128 + wc2 * 64 + n * 16 + fr;
        dsth[(long)co * NPOS + j] = __float2bfloat16(acc[m][n][r_]);
      }
    }
  }
  #undef STAGE_A
  #undef STAGE_B
  #undef READ_H2
  #undef MFMA16
  #undef WAITV4
  #undef WAITV0
  #undef BAR
}

// ---------------- fused 1x1 heads: sum partials + BN1/ReLU + heads + softmax/BN/reshape
__global__ __launch_bounds__(256) void head_fused(
    const __hip_bfloat16* __restrict__ h0, const __hip_bfloat16* __restrict__ h1,
    const float* __restrict__ Wh,
    const float* __restrict__ inv1, const float* __restrict__ add1,
    const float* __restrict__ bsel, const float* __restrict__ bbox,
    const float* __restrict__ gb, const float* __restrict__ beb,
    const float* __restrict__ mub, const float* __restrict__ vab,
    float* __restrict__ out)
{
  __shared__ float red[4 * 64 * 54];
  const int t = threadIdx.x;
  const int jl = t & 63;
  const int cg = __builtin_amdgcn_readfirstlane(t >> 6);  // 0..3, wave-uniform
  const int j0 = blockIdx.x * 64;
  const int j = j0 + jl;

  float acc[54];
  #pragma unroll
  for (int o = 0; o < 54; ++o) acc[o] = 0.f;

  const __hip_bfloat16* hp0 = h0 + (long)(cg * 256) * NPOS + j;
  const __hip_bfloat16* hp1 = h1 + (long)(cg * 256) * NPOS + j;
  const float* wp = Wh + cg * 256 * 54;
  const float* ivp = inv1 + cg * 256;
  const float* adp = add1 + cg * 256;
  for (int i = 0; i < 256; ++i) {
    float hv = __bfloat162float(hp0[(long)i * NPOS]) + __bfloat162float(hp1[(long)i * NPOS]);
    hv = fmaxf(hv * ivp[i] + adp[i], 0.f);   // fused bias+BN1+ReLU
    const float* wr_ = wp + i * 54;
    #pragma unroll
    for (int o = 0; o < 54; ++o) acc[o] += hv * wr_[o];
  }
  #pragma unroll
  for (int o = 0; o < 54; ++o) red[(cg * 64 + jl) * 54 + o] = acc[o];
  __syncthreads();

  // scores: 64 j x 9 pairs -> relu -> softmax over pair
  for (int idx = t; idx < 576; idx += 256) {
    int jj = idx / 9, pr = idx % 9;
    float s0 = bsel[2 * pr], s1 = bsel[2 * pr + 1];
    #pragma unroll
    for (int c = 0; c < 4; ++c) {
      s0 += red[(c * 64 + jj) * 54 + 2 * pr];
      s1 += red[(c * 64 + jj) * 54 + 2 * pr + 1];
    }
    s0 = fmaxf(s0, 0.f); s1 = fmaxf(s1, 0.f);
    float mx = fmaxf(s0, s1);
    float e0 = expf(s0 - mx), e1 = expf(s1 - mx);
    float inv = 1.f / (e0 + e1);
    int jg = j0 + jj;
    int nn = jg / HWSP, p = jg % HWSP;
    long off = ((long)nn * 1764 + p * 9 + pr) * 2;
    out[off] = e0 * inv;
    out[off + 1] = e1 * inv;
  }

  // boxes: 64 j x 36 -> BN -> relu -> *419
  float* outb = out + (long)NB * 1764 * 2;
  for (int idx = t; idx < 2304; idx += 256) {
    int jj = idx / 36, o = idx % 36;
    float v = bbox[o];
    #pragma unroll
    for (int c = 0; c < 4; ++c) v += red[(c * 64 + jj) * 54 + 18 + o];
    float iv = gb[o] / sqrtf(vab[o] + 1e-5f);
    v = v * iv + (beb[o] - mub[o] * iv);
    v = fmaxf(v, 0.f) * 419.f;
    int jg = j0 + jj;
    int nn = jg / HWSP, p = jg % HWSP;
    outb[((long)nn * 1764 + p * 9 + (o >> 2)) * 4 + (o & 3)] = v;
  }
}

extern "C" void kernel_launch(void* const* d_in, const int* in_sizes, int n_in,
                              void* d_out, int out_size, void* d_ws, size_t ws_size,
                              hipStream_t stream) {
  const float* x    = (const float*)d_in[0];
  const float* w1   = (const float*)d_in[1];
  const float* b1   = (const float*)d_in[2];
  const float* g1   = (const float*)d_in[3];
  const float* be1  = (const float*)d_in[4];
  const float* mu1  = (const float*)d_in[5];
  const float* va1  = (const float*)d_in[6];
  const float* wsel = (const float*)d_in[7];
  const float* bsel = (const float*)d_in[8];
  const float* wbox = (const float*)d_in[9];
  const float* bbox = (const float*)d_in[10];
  const float* gb   = (const float*)d_in[11];
  const float* beb  = (const float*)d_in[12];
  const float* mub  = (const float*)d_in[13];
  const float* vab  = (const float*)d_in[14];

  char* ws = (char*)d_ws;
  __hip_bfloat16* Wp = (__hip_bfloat16*)(ws);                    // 9*1024*2048*2   = 37748736
  __hip_bfloat16* Xp = (__hip_bfloat16*)(ws + 37748736);         // 32*256*2048*2   = 33554432
  __hip_bfloat16* hb0 = (__hip_bfloat16*)(ws + 71303168);        // 1024*6272*2     = 12845056
  __hip_bfloat16* hb1 = (__hip_bfloat16*)(ws + 84148224);        // 1024*6272*2     = 12845056
  float* inv1        = (float*)(ws + 96993280);                  // 4096
  float* add1        = (float*)(ws + 96997376);                  // 4096
  float* Wh          = (float*)(ws + 97001472);                  // 1024*54*4       = 221184

  hipLaunchKernelGGL(pack_all, dim3(9216), dim3(256), 0, stream,
                     w1, b1, g1, be1, mu1, va1, wsel, wbox, x, Wp, inv1, add1, Wh, Xp);
  hipLaunchKernelGGL(conv_mfma, dim3(448, 2), dim3(256), 0, stream,
                     Wp, Xp, hb0, hb1);
  hipLaunchKernelGGL(head_fused, dim3(98), dim3(256), 0, stream,
                     hb0, hb1, Wh, inv1, add1, bsel, bbox, gb, beb, mub, vab, (float*)d_out);
}

// Round 15
// 392.240 us; speedup vs baseline: 1.2150x; 1.0533x over previous
//
#include <hip/hip_runtime.h>
#include <hip/hip_bf16.h>
#include <math.h>

#define CIN   2048
#define CMID  1024
#define NB    32
#define HWSP  196
#define NPOS  6272      // 32*196
#define WELEM 2097152   // CMID*CIN
#define NSTEP 192       // K32-steps per z-chunk (3 taps x 64)

typedef __attribute__((ext_vector_type(4))) float f32x4;
typedef __attribute__((ext_vector_type(8))) short short8;
typedef __attribute__((ext_vector_type(4))) float float4v;

typedef const __attribute__((address_space(1))) unsigned int* as1_u32p;
typedef __attribute__((address_space(3))) unsigned int* as3_u32p;

__device__ __forceinline__ void gload_lds16(const void* g, void* l) {
  __builtin_amdgcn_global_load_lds((as1_u32p)g, (as3_u32p)l, 16, 0, 0);
}

// ---------------- fused packing: blocks [0,8192) pack W (LDS-transposed), blocks [8192,9216) pack X
__global__ __launch_bounds__(256) void pack_all(
    const float* __restrict__ w1, const float* __restrict__ b1,
    const float* __restrict__ g1, const float* __restrict__ be1,
    const float* __restrict__ mu1, const float* __restrict__ va1,
    const float* __restrict__ wsel, const float* __restrict__ wbox,
    const float* __restrict__ x,
    __hip_bfloat16* __restrict__ Wp, float* __restrict__ inv1,
    float* __restrict__ add1, float* __restrict__ Wh,
    __hip_bfloat16* __restrict__ Xp)
{
  __shared__ char shm[25088];
  if (blockIdx.x < 8192) {
    float* lw = (float*)shm;     // 256 gid x 9 taps
    const int gid0 = blockIdx.x * 256;
    const float4v* src4 = (const float4v*)(w1 + (long)gid0 * 9);
    float4v* l4 = (float4v*)lw;
    #pragma unroll
    for (int i = 0; i < 3; ++i) {
      int idx = i * 256 + threadIdx.x;
      if (idx < 576) l4[idx] = src4[idx];
    }
    __syncthreads();
    const int gid = gid0 + threadIdx.x;
    float v[9];
    #pragma unroll
    for (int k = 0; k < 9; ++k) v[k] = lw[threadIdx.x * 9 + k];
    #pragma unroll
    for (int k = 0; k < 9; ++k)
      Wp[(long)k * WELEM + gid] = __float2bfloat16(v[k]);

    if (gid < CMID) {
      float iv = g1[gid] / sqrtf(va1[gid] + 1e-5f);
      inv1[gid] = iv;
      add1[gid] = b1[gid] * iv + be1[gid] - mu1[gid] * iv;
    }
    if (gid < CMID * 54) {
      int co = gid / 54, o = gid % 54;
      Wh[gid] = (o < 18) ? wsel[o * CMID + co] : wbox[(o - 18) * CMID + co];
    }
  } else {
    __hip_bfloat16* lx = (__hip_bfloat16*)shm;   // 64 ci x 196 pos
    const int b = blockIdx.x - 8192;
    const int n = b >> 5;          // 0..31
    const int cc = b & 31;         // 0..31
    const int ci0 = cc * 64;
    const float* src = x + ((long)n * CIN + ci0) * HWSP;
    for (int i = threadIdx.x; i < 64 * HWSP; i += 256)
      lx[i] = __float2bfloat16(src[i]);
    __syncthreads();
    const int ci = threadIdx.x & 63;
    const int pq = threadIdx.x >> 6;   // 0..3
    __hip_bfloat16* dst = Xp + (long)n * 256 * CIN + ci0 + ci;
    const __hip_bfloat16 z = __float2bfloat16(0.f);
    #pragma unroll
    for (int k = 0; k < 64; ++k) {
      int pos = k * 4 + pq;
      int y = pos >> 4, xx = pos & 15;
      __hip_bfloat16 v = z;
      if (y >= 1 && y <= 14 && xx >= 1 && xx <= 14)
        v = lx[ci * HWSP + (y - 1) * 14 + (xx - 1)];
      dst[(long)pos * CIN] = v;
    }
  }
}

// ---------------- conv 3x3 as shifted GEMMs, split-K thirds (3 taps / 192 BK32-steps each)
// 256x128 tile, 4 waves x (128x64) wave tile (acc[8][4]), 16x16x32 bf16 MFMA.
// __launch_bounds__(256,2) -> 256-VGPR cap: acc stays in unified regfile, NO AGPR shuttle
// (R4/R9's VALU 51% failure mode). Dbuf 2x24KB. Per step: vmcnt0+lgkm0+BAR,
// STAGE(s+1) post-BAR (race-free), READ frags, setprio MFMA x32. XCD remap for B locality.
__global__ __launch_bounds__(256, 2) void conv_mfma(
    const __hip_bfloat16* __restrict__ Wp,
    const __hip_bfloat16* __restrict__ Xp,
    __hip_bfloat16* __restrict__ hout0,
    __hip_bfloat16* __restrict__ hout1,
    __hip_bfloat16* __restrict__ hout2)
{
  __shared__ char smem[2 * 24576];   // per buffer: A 16KB (256x32) | B 8KB (128x32)

  const int t = threadIdx.x;
  // grid.x = 224: r = XCD slot, q = bx>>3 (0..27): kidx = q>>2, mtile = q&3
  const int bx = blockIdx.x;
  const int r  = bx & 7;
  const int q  = bx >> 3;
  const int kidx = q >> 2;         // 0..6
  const int mtile = q & 3;
  int ntile;
  if (kidx < 6) {
    ntile = r + 8 * kidx;          // XCD r owns ntiles {r, r+8, ..., r+40}
  } else {
    if (r != ((q & 3) << 1)) return;   // ntile 48: 4 blocks (one per mtile), XCDs 0/2/4/6
    ntile = 48;
  }
  const int z = blockIdx.y;        // 0..2
  const int lane = t & 63;
  const int wv = t >> 6;          // 0..3
  const int wr2 = wv >> 1;        // 0..1 -> M offset *128
  const int wc2 = wv & 1;         // 0..1 -> N offset *64

  // staging: thread t covers A rows (t>>2)+64i (i<4), B rows (t>>2)+64i (i<2); XOR-preswizzled
  const int srow = t >> 2;                                   // 0..63
  const int swb = ((t & 3) << 4) ^ ((srow & 6) << 3);        // byte offset in 64B row

  const long arowbase = (long)(mtile * 256 + srow) * CIN + (swb >> 1);

  long bbase[2];
  #pragma unroll
  for (int i = 0; i < 2; ++i) {
    int jj = ntile * 128 + srow + 64 * i;
    int n0 = jj / HWSP, p0 = jj % HWSP;
    int hh = p0 / 14, ww = p0 % 14;
    bbase[i] = (long)(n0 * 256 + hh * 16 + ww) * CIN + (swb >> 1);
  }

  // frag-read swizzle constant (row&6 == fr&6 for 16-aligned row bases)
  const int fr = lane & 15;
  const int ksl = lane >> 4;                                 // 0..3
  const int kgsw = ((ksl << 4) ^ ((fr & 6) << 3));

  f32x4 acc[8][4] = {};
  short8 a_[8], b_[4];

  const int tap0 = z * 3;

  #define STAGE(gv, bi) do {                                                    \
    int g_ = (gv);                                                              \
    int kt_ = tap0 + (g_ >> 6);                                                 \
    int ck_ = (g_ & 63) << 5;                                                   \
    int kh_ = (kt_ * 11) >> 5;                                                  \
    int kw_ = kt_ - kh_ * 3;                                                    \
    char* d_ = smem + (bi) * 24576;                                             \
    const __hip_bfloat16* ap_ = Wp + (long)kt_ * WELEM + arowbase + ck_;        \
    _Pragma("unroll")                                                           \
    for (int i_ = 0; i_ < 4; ++i_)                                              \
      gload_lds16(ap_ + (long)i_ * 64 * CIN, d_ + i_ * 4096 + t * 16);          \
    long boff_ = (long)(kh_ * 16 + kw_) * CIN + ck_;                            \
    _Pragma("unroll")                                                           \
    for (int i_ = 0; i_ < 2; ++i_)                                              \
      gload_lds16(Xp + bbase[i_] + boff_, d_ + 16384 + i_ * 4096 + t * 16);     \
  } while (0)

  #define READF(bi) do {                                                        \
    const char* cb_ = smem + (bi) * 24576;                                      \
    _Pragma("unroll")                                                           \
    for (int i = 0; i < 8; ++i)                                                 \
      a_[i] = *(const short8*)(cb_ + (wr2 * 128 + i * 16 + fr) * 64 + kgsw);    \
    _Pragma("unroll")                                                           \
    for (int i = 0; i < 4; ++i)                                                 \
      b_[i] = *(const short8*)(cb_ + 16384 + (wc2 * 64 + i * 16 + fr) * 64 + kgsw); \
  } while (0)

  #define MFMA32() do {                                                         \
    __builtin_amdgcn_s_setprio(1);                                              \
    _Pragma("unroll")                                                           \
    for (int m = 0; m < 8; ++m)                                                 \
      _Pragma("unroll")                                                         \
      for (int n = 0; n < 4; ++n)                                               \
        acc[m][n] = __builtin_amdgcn_mfma_f32_16x16x32_bf16(a_[m], b_[n], acc[m][n], 0, 0, 0); \
    __builtin_amdgcn_s_setprio(0);                                              \
  } while (0)

  #define WAITV0() asm volatile("s_waitcnt vmcnt(0)" ::: "memory")
  #define LGKM0()  asm volatile("s_waitcnt lgkmcnt(0)" ::: "memory")
  #define BAR() do { asm volatile("" ::: "memory");                             \
                     __builtin_amdgcn_s_barrier();                              \
                     asm volatile("" ::: "memory"); } while (0)

  STAGE(0, 0);
  for (int s = 0; s < NSTEP - 1; ++s) {
    WAITV0();                   // stage(s) landed (issued a full step ago; latency covered)
    LGKM0();                    // prior step's ds_reads complete before anyone passes BAR
    BAR();                      // publish stage(s); fence buf[(s+1)&1] overwrite
    STAGE(s + 1, (s + 1) & 1);  // post-BAR: race-free vs step s-1 readers
    READF(s & 1);
    MFMA32();
  }
  WAITV0(); LGKM0(); BAR();
  READF((NSTEP - 1) & 1);
  MFMA32();

  // epilogue: bf16 raw conv partials (BN/ReLU fused in head)
  __hip_bfloat16* dsth = (z == 0) ? hout0 : (z == 1) ? hout1 : hout2;
  const int rg = ksl * 4;
  #pragma unroll
  for (int m = 0; m < 8; ++m) {
    const int co0 = mtile * 256 + wr2 * 128 + m * 16 + rg;
    #pragma unroll
    for (int r_ = 0; r_ < 4; ++r_) {
      const int co = co0 + r_;
      #pragma unroll
      for (int n = 0; n < 4; ++n) {
        const int j = ntile * 128 + wc2 * 64 + n * 16 + fr;
        dsth[(long)co * NPOS + j] = __float2bfloat16(acc[m][n][r_]);
      }
    }
  }
  #undef STAGE
  #undef READF
  #undef MFMA32
  #undef WAITV0
  #undef LGKM0
  #undef BAR
}

// ---------------- fused 1x1 heads: 512 thr, 8 x 128-channel groups, two-pass LDS reduce
__global__ __launch_bounds__(512) void head_fused(
    const __hip_bfloat16* __restrict__ h0, const __hip_bfloat16* __restrict__ h1,
    const __hip_bfloat16* __restrict__ h2,
    const float* __restrict__ Wh,
    const float* __restrict__ inv1, const float* __restrict__ add1,
    const float* __restrict__ bsel, const float* __restrict__ bbox,
    const float* __restrict__ gb, const float* __restrict__ beb,
    const float* __restrict__ mub, const float* __restrict__ vab,
    float* __restrict__ out)
{
  __shared__ float red[4 * 64 * 54];   // 55.3 KB
  const int t = threadIdx.x;
  const int jl = t & 63;
  const int cg = __builtin_amdgcn_readfirstlane(t >> 6);  // 0..7, wave-uniform
  const int j0 = blockIdx.x * 64;
  const int j = j0 + jl;

  float acc[54];
  #pragma unroll
  for (int o = 0; o < 54; ++o) acc[o] = 0.f;

  const __hip_bfloat16* hp0 = h0 + (long)(cg * 128) * NPOS + j;
  const __hip_bfloat16* hp1 = h1 + (long)(cg * 128) * NPOS + j;
  const __hip_bfloat16* hp2 = h2 + (long)(cg * 128) * NPOS + j;
  const float* wp = Wh + cg * 128 * 54;
  const float* ivp = inv1 + cg * 128;
  const float* adp = add1 + cg * 128;
  for (int i = 0; i < 128; ++i) {
    float hv = __bfloat162float(hp0[(long)i * NPOS])
             + __bfloat162float(hp1[(long)i * NPOS])
             + __bfloat162float(hp2[(long)i * NPOS]);
    hv = fmaxf(hv * ivp[i] + adp[i], 0.f);   // fused bias+BN1+ReLU
    const float* wr_ = wp + i * 54;
    #pragma unroll
    for (int o = 0; o < 54; ++o) acc[o] += hv * wr_[o];
  }
  // two-pass reduce: groups 0-3 write, groups 4-7 accumulate
  if (cg < 4) {
    #pragma unroll
    for (int o = 0; o < 54; ++o) red[(cg * 64 + jl) * 54 + o] = acc[o];
  }
  __syncthreads();
  if (cg >= 4) {
    #pragma unroll
    for (int o = 0; o < 54; ++o) red[((cg - 4) * 64 + jl) * 54 + o] += acc[o];
  }
  __syncthreads();

  // scores: 64 j x 9 pairs -> relu -> softmax over pair
  for (int idx = t; idx < 576; idx += 512) {
    int jj = idx / 9, pr = idx % 9;
    float s0 = bsel[2 * pr], s1 = bsel[2 * pr + 1];
    #pragma unroll
    for (int c = 0; c < 4; ++c) {
      s0 += red[(c * 64 + jj) * 54 + 2 * pr];
      s1 += red[(c * 64 + jj) * 54 + 2 * pr + 1];
    }
    s0 = fmaxf(s0, 0.f); s1 = fmaxf(s1, 0.f);
    float mx = fmaxf(s0, s1);
    float e0 = expf(s0 - mx), e1 = expf(s1 - mx);
    float inv = 1.f / (e0 + e1);
    int jg = j0 + jj;
    int nn = jg / HWSP, p = jg % HWSP;
    long off = ((long)nn * 1764 + p * 9 + pr) * 2;
    out[off] = e0 * inv;
    out[off + 1] = e1 * inv;
  }

  // boxes: 64 j x 36 -> BN -> relu -> *419
  float* outb = out + (long)NB * 1764 * 2;
  for (int idx = t; idx < 2304; idx += 512) {
    int jj = idx / 36, o = idx % 36;
    float v = bbox[o];
    #pragma unroll
    for (int c = 0; c < 4; ++c) v += red[(c * 64 + jj) * 54 + 18 + o];
    float iv = gb[o] / sqrtf(vab[o] + 1e-5f);
    v = v * iv + (beb[o] - mub[o] * iv);
    v = fmaxf(v, 0.f) * 419.f;
    int jg = j0 + jj;
    int nn = jg / HWSP, p = jg % HWSP;
    outb[((long)nn * 1764 + p * 9 + (o >> 2)) * 4 + (o & 3)] = v;
  }
}

extern "C" void kernel_launch(void* const* d_in, const int* in_sizes, int n_in,
                              void* d_out, int out_size, void* d_ws, size_t ws_size,
                              hipStream_t stream) {
  const float* x    = (const float*)d_in[0];
  const float* w1   = (const float*)d_in[1];
  const float* b1   = (const float*)d_in[2];
  const float* g1   = (const float*)d_in[3];
  const float* be1  = (const float*)d_in[4];
  const float* mu1  = (const float*)d_in[5];
  const float* va1  = (const float*)d_in[6];
  const float* wsel = (const float*)d_in[7];
  const float* bsel = (const float*)d_in[8];
  const float* wbox = (const float*)d_in[9];
  const float* bbox = (const float*)d_in[10];
  const float* gb   = (const float*)d_in[11];
  const float* beb  = (const float*)d_in[12];
  const float* mub  = (const float*)d_in[13];
  const float* vab  = (const float*)d_in[14];

  char* ws = (char*)d_ws;
  __hip_bfloat16* Wp = (__hip_bfloat16*)(ws);                    // 9*1024*2048*2   = 37748736
  __hip_bfloat16* Xp = (__hip_bfloat16*)(ws + 37748736);         // 32*256*2048*2   = 33554432
  __hip_bfloat16* hb0 = (__hip_bfloat16*)(ws + 71303168);        // 1024*6272*2     = 12845056
  __hip_bfloat16* hb1 = (__hip_bfloat16*)(ws + 84148224);        // 1024*6272*2     = 12845056
  __hip_bfloat16* hb2 = (__hip_bfloat16*)(ws + 96993280);        // 1024*6272*2     = 12845056
  float* inv1        = (float*)(ws + 109838336);                 // 4096
  float* add1        = (float*)(ws + 109842432);                 // 4096
  float* Wh          = (float*)(ws + 109846528);                 // 1024*54*4       = 221184

  hipLaunchKernelGGL(pack_all, dim3(9216), dim3(256), 0, stream,
                     w1, b1, g1, be1, mu1, va1, wsel, wbox, x, Wp, inv1, add1, Wh, Xp);
  hipLaunchKernelGGL(conv_mfma, dim3(224, 3), dim3(256), 0, stream,
                     Wp, Xp, hb0, hb1, hb2);
  hipLaunchKernelGGL(head_fused, dim3(98), dim3(512), 0, stream,
                     hb0, hb1, hb2, Wh, inv1, add1, bsel, bbox, gb, beb, mub, vab, (float*)d_out);
}

// Round 16
// 357.582 us; speedup vs baseline: 1.3327x; 1.0969x over previous
//
#include <hip/hip_runtime.h>
#include <hip/hip_bf16.h>
#include <math.h>

#define CIN   2048
#define CMID  1024
#define NB    32
#define HWSP  196
#define NPOS  6272      // 32*196
#define WELEM 2097152   // CMID*CIN
#define NST64 144       // K64-steps per z-chunk (total K=18432 split in 2)

typedef __attribute__((ext_vector_type(4))) float f32x4;
typedef __attribute__((ext_vector_type(8))) short short8;
typedef __attribute__((ext_vector_type(4))) float float4v;

typedef const __attribute__((address_space(1))) unsigned int* as1_u32p;
typedef __attribute__((address_space(3))) unsigned int* as3_u32p;

__device__ __forceinline__ void gload_lds16(const void* g, void* l) {
  __builtin_amdgcn_global_load_lds((as1_u32p)g, (as3_u32p)l, 16, 0, 0);
}

// ---------------- fused packing: blocks [0,8192) pack W (LDS-transposed), blocks [8192,9216) pack X
__global__ __launch_bounds__(256) void pack_all(
    const float* __restrict__ w1, const float* __restrict__ b1,
    const float* __restrict__ g1, const float* __restrict__ be1,
    const float* __restrict__ mu1, const float* __restrict__ va1,
    const float* __restrict__ wsel, const float* __restrict__ wbox,
    const float* __restrict__ x,
    __hip_bfloat16* __restrict__ Wp, float* __restrict__ inv1,
    float* __restrict__ add1, float* __restrict__ Wh,
    __hip_bfloat16* __restrict__ Xp)
{
  __shared__ char shm[25088];
  if (blockIdx.x < 8192) {
    float* lw = (float*)shm;     // 256 gid x 9 taps
    const int gid0 = blockIdx.x * 256;
    const float4v* src4 = (const float4v*)(w1 + (long)gid0 * 9);
    float4v* l4 = (float4v*)lw;
    #pragma unroll
    for (int i = 0; i < 3; ++i) {
      int idx = i * 256 + threadIdx.x;
      if (idx < 576) l4[idx] = src4[idx];
    }
    __syncthreads();
    const int gid = gid0 + threadIdx.x;
    float v[9];
    #pragma unroll
    for (int k = 0; k < 9; ++k) v[k] = lw[threadIdx.x * 9 + k];
    #pragma unroll
    for (int k = 0; k < 9; ++k)
      Wp[(long)k * WELEM + gid] = __float2bfloat16(v[k]);

    if (gid < CMID) {
      float iv = g1[gid] / sqrtf(va1[gid] + 1e-5f);
      inv1[gid] = iv;
      add1[gid] = b1[gid] * iv + be1[gid] - mu1[gid] * iv;
    }
    if (gid < CMID * 54) {
      int co = gid / 54, o = gid % 54;
      Wh[gid] = (o < 18) ? wsel[o * CMID + co] : wbox[(o - 18) * CMID + co];
    }
  } else {
    __hip_bfloat16* lx = (__hip_bfloat16*)shm;   // 64 ci x 196 pos
    const int b = blockIdx.x - 8192;
    const int n = b >> 5;          // 0..31
    const int cc = b & 31;         // 0..31
    const int ci0 = cc * 64;
    const float* src = x + ((long)n * CIN + ci0) * HWSP;
    for (int i = threadIdx.x; i < 64 * HWSP; i += 256)
      lx[i] = __float2bfloat16(src[i]);
    __syncthreads();
    const int ci = threadIdx.x & 63;
    const int pq = threadIdx.x >> 6;   // 0..3
    __hip_bfloat16* dst = Xp + (long)n * 256 * CIN + ci0 + ci;
    const __hip_bfloat16 z = __float2bfloat16(0.f);
    #pragma unroll
    for (int k = 0; k < 64; ++k) {
      int pos = k * 4 + pq;
      int y = pos >> 4, xx = pos & 15;
      __hip_bfloat16 v = z;
      if (y >= 1 && y <= 14 && xx >= 1 && xx <= 14)
        v = lx[ci * HWSP + (y - 1) * 14 + (xx - 1)];
      dst[(long)pos * CIN] = v;
    }
  }
}

// ---------------- conv 3x3 as shifted GEMMs, split-K halves (144 BK64-steps each)
// [R11 verbatim — best measured: 272us, MfmaUtil 40%]
// 128x128 tile, 4 waves x (64x64), 16x16x32 bf16 MFMA.
// BK=64 double-buffer (2x32KB). Per step: 2 phases {stage-issue, counted vmcnt(4), bar,
// ds_read k-half, setprio MFMA}. Loads span phases (T4); phase split feeds setprio (T5).
__global__ __launch_bounds__(256, 2) void conv_mfma(
    const __hip_bfloat16* __restrict__ Wp,
    const __hip_bfloat16* __restrict__ Xp,
    __hip_bfloat16* __restrict__ hout0,
    __hip_bfloat16* __restrict__ hout1)
{
  __shared__ char smem[2 * 32768];   // per buffer: A_k0 8K | A_k1 8K | B_k0 8K | B_k1 8K

  const int t = threadIdx.x;
  // grid.x = 448: r = XCD slot, q>>3 = ntile column, q&7 = mtile
  const int bx = blockIdx.x;
  const int r  = bx & 7;
  const int q  = bx >> 3;          // 0..55
  const int kidx = q >> 3;         // 0..6
  int mtile = q & 7;
  int ntile;
  if (kidx < 6) {
    ntile = r + 8 * kidx;          // XCD r owns ntiles {r, r+8, ..., r+40}
  } else {
    if (r != (q & 7)) return;      // ntile 48: one block per XCD (balanced)
    ntile = 48;
  }
  const int z = blockIdx.y;        // 0..1
  const int lane = t & 63;
  const int wv = t >> 6;          // 0..3
  const int wr2 = wv >> 1;        // 0..1 -> M offset *64
  const int wc2 = wv & 1;         // 0..1 -> N offset *64

  // staging: thread t covers rows (t>>2)(+64), 16B chunk (t&3), XOR-preswizzled source
  const int srow = t >> 2;                                   // 0..63
  const int swb = ((t & 3) << 4) ^ ((srow & 6) << 3);        // byte offset in 64B row

  const long arowbase = (long)(mtile * 128 + srow) * CIN + (swb >> 1);

  long bbase[2];
  #pragma unroll
  for (int i = 0; i < 2; ++i) {
    int jj = ntile * 128 + srow + 64 * i;
    int n0 = jj / HWSP, p0 = jj % HWSP;
    int hh = p0 / 14, ww = p0 % 14;
    bbase[i] = (long)(n0 * 256 + hh * 16 + ww) * CIN + (swb >> 1);
  }

  // frag-read swizzle constant
  const int fr = lane & 15;
  const int ksl = lane >> 4;                                 // 0..3
  const int kgsw = ((ksl << 4) ^ ((fr & 6) << 3));

  f32x4 acc[4][4] = {};
  short8 a_[4], b_[4];

  const int g0 = z * NST64;

  // K64 step g: tap kt = g>>5
  #define STAGE_A(gv, bi) do {                                                  \
    int g_ = (gv);                                                              \
    int kt_ = g_ >> 5;                                                          \
    int ck_ = (g_ & 31) << 6;                                                   \
    char* d_ = smem + (bi) * 32768;                                             \
    const __hip_bfloat16* ap_ = Wp + (long)kt_ * WELEM + arowbase + ck_;        \
    _Pragma("unroll")                                                           \
    for (int h_ = 0; h_ < 2; ++h_)                                              \
      _Pragma("unroll")                                                         \
      for (int i_ = 0; i_ < 2; ++i_)                                            \
        gload_lds16(ap_ + h_ * 32 + (long)i_ * 64 * CIN,                        \
                    d_ + h_ * 8192 + i_ * 4096 + t * 16);                       \
  } while (0)

  #define STAGE_B(gv, bi) do {                                                  \
    int g_ = (gv);                                                              \
    int kt_ = g_ >> 5;                                                          \
    int ck_ = (g_ & 31) << 6;                                                   \
    int kh_ = (kt_ * 11) >> 5;                                                  \
    int kw_ = kt_ - kh_ * 3;                                                    \
    char* d_ = smem + (bi) * 32768 + 16384;                                     \
    long boff_ = (long)(kh_ * 16 + kw_) * CIN + ck_;                            \
    _Pragma("unroll")                                                           \
    for (int h_ = 0; h_ < 2; ++h_)                                              \
      _Pragma("unroll")                                                         \
      for (int i_ = 0; i_ < 2; ++i_)                                            \
        gload_lds16(Xp + bbase[i_] + boff_ + h_ * 32,                           \
                    d_ + h_ * 8192 + i_ * 4096 + t * 16);                       \
  } while (0)

  #define READ_H(bi, h) do {                                                    \
    const char* cb_ = smem + (bi) * 32768 + (h) * 8192;                         \
    _Pragma("unroll")                                                           \
    for (int i = 0; i < 4; ++i)                                                 \
      a_[i] = *(const short8*)(cb_ + (wr2 * 64 + i * 16 + fr) * 64 + kgsw);     \
    _Pragma("unroll")                                                           \
    for (int i = 0; i < 4; ++i)                                                 \
      b_[i] = *(const short8*)(cb_ + 16384 + (wc2 * 64 + i * 16 + fr) * 64 + kgsw); \
  } while (0)

  #define MFMA_H() do {                                                         \
    __builtin_amdgcn_s_setprio(1);                                              \
    _Pragma("unroll")                                                           \
    for (int m = 0; m < 4; ++m)                                                 \
      _Pragma("unroll")                                                         \
      for (int n = 0; n < 4; ++n)                                               \
        acc[m][n] = __builtin_amdgcn_mfma_f32_16x16x32_bf16(a_[m], b_[n], acc[m][n], 0, 0, 0); \
    __builtin_amdgcn_s_setprio(0);                                              \
  } while (0)

  #define WAITV4() asm volatile("s_waitcnt vmcnt(4)" ::: "memory")
  #define WAITV0() asm volatile("s_waitcnt vmcnt(0)" ::: "memory")
  #define BAR() do { asm volatile("" ::: "memory");                             \
                     __builtin_amdgcn_s_barrier();                              \
                     asm volatile("" ::: "memory"); } while (0)

  // prologue: stage(0) fully (8 loads)
  STAGE_A(g0 + 0, 0);
  STAGE_B(g0 + 0, 0);

  for (int s = 0; s < NST64 - 1; ++s) {
    const int c = s & 1, n = c ^ 1;
    // phase 0: issue A-stage(s+1); retire stage(s); compute k-half 0
    STAGE_A(g0 + s + 1, n);     // outstanding: stage(s) 8 + 4 = 12
    WAITV4();                   // retires stage(s); my 4 A-loads remain in flight
    BAR();                      // stage(s) visible; prev-step reads done
    READ_H(c, 0);
    MFMA_H();
    // phase 1: issue B-stage(s+1); compute k-half 1
    STAGE_B(g0 + s + 1, n);     // outstanding: 8
    READ_H(c, 1);
    BAR();                      // reads of buf[c] complete before next-step overwrite
    MFMA_H();
  }
  // final step
  {
    const int c = (NST64 - 1) & 1;
    WAITV0(); BAR();
    READ_H(c, 0);
    MFMA_H();
    READ_H(c, 1);
    MFMA_H();
  }

  // epilogue: bf16 raw conv partials (BN/ReLU fused in head)
  __hip_bfloat16* dsth = z ? hout1 : hout0;
  const int rg = ksl * 4;
  #pragma unroll
  for (int m = 0; m < 4; ++m) {
    const int co0 = mtile * 128 + wr2 * 64 + m * 16 + rg;
    #pragma unroll
    for (int r_ = 0; r_ < 4; ++r_) {
      const int co = co0 + r_;
      #pragma unroll
      for (int n = 0; n < 4; ++n) {
        const int j = ntile * 128 + wc2 * 64 + n * 16 + fr;
        dsth[(long)co * NPOS + j] = __float2bfloat16(acc[m][n][r_]);
      }
    }
  }
  #undef STAGE_A
  #undef STAGE_B
  #undef READ_H
  #undef MFMA_H
  #undef WAITV4
  #undef WAITV0
  #undef BAR
}

// ---------------- fused 1x1 heads: 512 thr, 8 x 128-channel groups, two-pass LDS reduce
__global__ __launch_bounds__(512) void head_fused(
    const __hip_bfloat16* __restrict__ h0, const __hip_bfloat16* __restrict__ h1,
    const float* __restrict__ Wh,
    const float* __restrict__ inv1, const float* __restrict__ add1,
    const float* __restrict__ bsel, const float* __restrict__ bbox,
    const float* __restrict__ gb, const float* __restrict__ beb,
    const float* __restrict__ mub, const float* __restrict__ vab,
    float* __restrict__ out)
{
  __shared__ float red[4 * 64 * 54];   // 55.3 KB
  const int t = threadIdx.x;
  const int jl = t & 63;
  const int cg = __builtin_amdgcn_readfirstlane(t >> 6);  // 0..7, wave-uniform
  const int j0 = blockIdx.x * 64;
  const int j = j0 + jl;

  float acc[54];
  #pragma unroll
  for (int o = 0; o < 54; ++o) acc[o] = 0.f;

  const __hip_bfloat16* hp0 = h0 + (long)(cg * 128) * NPOS + j;
  const __hip_bfloat16* hp1 = h1 + (long)(cg * 128) * NPOS + j;
  const float* wp = Wh + cg * 128 * 54;
  const float* ivp = inv1 + cg * 128;
  const float* adp = add1 + cg * 128;
  for (int i = 0; i < 128; ++i) {
    float hv = __bfloat162float(hp0[(long)i * NPOS]) + __bfloat162float(hp1[(long)i * NPOS]);
    hv = fmaxf(hv * ivp[i] + adp[i], 0.f);   // fused bias+BN1+ReLU
    const float* wr_ = wp + i * 54;
    #pragma unroll
    for (int o = 0; o < 54; ++o) acc[o] += hv * wr_[o];
  }
  // two-pass reduce: groups 0-3 write, groups 4-7 accumulate
  if (cg < 4) {
    #pragma unroll
    for (int o = 0; o < 54; ++o) red[(cg * 64 + jl) * 54 + o] = acc[o];
  }
  __syncthreads();
  if (cg >= 4) {
    #pragma unroll
    for (int o = 0; o < 54; ++o) red[((cg - 4) * 64 + jl) * 54 + o] += acc[o];
  }
  __syncthreads();

  // scores: 64 j x 9 pairs -> relu -> softmax over pair
  for (int idx = t; idx < 576; idx += 512) {
    int jj = idx / 9, pr = idx % 9;
    float s0 = bsel[2 * pr], s1 = bsel[2 * pr + 1];
    #pragma unroll
    for (int c = 0; c < 4; ++c) {
      s0 += red[(c * 64 + jj) * 54 + 2 * pr];
      s1 += red[(c * 64 + jj) * 54 + 2 * pr + 1];
    }
    s0 = fmaxf(s0, 0.f); s1 = fmaxf(s1, 0.f);
    float mx = fmaxf(s0, s1);
    float e0 = expf(s0 - mx), e1 = expf(s1 - mx);
    float inv = 1.f / (e0 + e1);
    int jg = j0 + jj;
    int nn = jg / HWSP, p = jg % HWSP;
    long off = ((long)nn * 1764 + p * 9 + pr) * 2;
    out[off] = e0 * inv;
    out[off + 1] = e1 * inv;
  }

  // boxes: 64 j x 36 -> BN -> relu -> *419
  float* outb = out + (long)NB * 1764 * 2;
  for (int idx = t; idx < 2304; idx += 512) {
    int jj = idx / 36, o = idx % 36;
    float v = bbox[o];
    #pragma unroll
    for (int c = 0; c < 4; ++c) v += red[(c * 64 + jj) * 54 + 18 + o];
    float iv = gb[o] / sqrtf(vab[o] + 1e-5f);
    v = v * iv + (beb[o] - mub[o] * iv);
    v = fmaxf(v, 0.f) * 419.f;
    int jg = j0 + jj;
    int nn = jg / HWSP, p = jg % HWSP;
    outb[((long)nn * 1764 + p * 9 + (o >> 2)) * 4 + (o & 3)] = v;
  }
}

extern "C" void kernel_launch(void* const* d_in, const int* in_sizes, int n_in,
                              void* d_out, int out_size, void* d_ws, size_t ws_size,
                              hipStream_t stream) {
  const float* x    = (const float*)d_in[0];
  const float* w1   = (const float*)d_in[1];
  const float* b1   = (const float*)d_in[2];
  const float* g1   = (const float*)d_in[3];
  const float* be1  = (const float*)d_in[4];
  const float* mu1  = (const float*)d_in[5];
  const float* va1  = (const float*)d_in[6];
  const float* wsel = (const float*)d_in[7];
  const float* bsel = (const float*)d_in[8];
  const float* wbox = (const float*)d_in[9];
  const float* bbox = (const float*)d_in[10];
  const float* gb   = (const float*)d_in[11];
  const float* beb  = (const float*)d_in[12];
  const float* mub  = (const float*)d_in[13];
  const float* vab  = (const float*)d_in[14];

  char* ws = (char*)d_ws;
  __hip_bfloat16* Wp = (__hip_bfloat16*)(ws);                    // 9*1024*2048*2   = 37748736
  __hip_bfloat16* Xp = (__hip_bfloat16*)(ws + 37748736);         // 32*256*2048*2   = 33554432
  __hip_bfloat16* hb0 = (__hip_bfloat16*)(ws + 71303168);        // 1024*6272*2     = 12845056
  __hip_bfloat16* hb1 = (__hip_bfloat16*)(ws + 84148224);        // 1024*6272*2     = 12845056
  float* inv1        = (float*)(ws + 96993280);                  // 4096
  float* add1        = (float*)(ws + 96997376);                  // 4096
  float* Wh          = (float*)(ws + 97001472);                  // 1024*54*4       = 221184

  hipLaunchKernelGGL(pack_all, dim3(9216), dim3(256), 0, stream,
                     w1, b1, g1, be1, mu1, va1, wsel, wbox, x, Wp, inv1, add1, Wh, Xp);
  hipLaunchKernelGGL(conv_mfma, dim3(448, 2), dim3(256), 0, stream,
                     Wp, Xp, hb0, hb1);
  hipLaunchKernelGGL(head_fused, dim3(98), dim3(512), 0, stream,
                     hb0, hb1, Wh, inv1, add1, bsel, bbox, gb, beb, mub, vab, (float*)d_out);
}